// Round 4
// baseline (20641.322 us; speedup 1.0000x reference)
//
#include <hip/hip_runtime.h>
#include <hip/hip_cooperative_groups.h>
#include <math.h>

namespace cg = cooperative_groups;

#define BB 64
#define TT 512
#define FF 512
#define DIN 1024
#define HH 1024
#define G4 4096
#define DOUT 128

typedef _Float16 f16;
typedef _Float16 f16x8 __attribute__((ext_vector_type(8)));
typedef float f32x4 __attribute__((ext_vector_type(4)));

// A-fragment-linear layout for a [64 x 1024] fp16 activation matrix:
//   element (m=row 0..63, k=col 0..1023) lives at
//   ((k>>5)*4 + (m>>4))*512 + ((((k>>3)&3)<<4) | (m&15))*8 + (k&7)
// so a wave-load "base + lane*16B" yields the MFMA A-fragment directly.
__device__ __forceinline__ size_t afrag_off(int m, int k) {
    return (size_t)(((k >> 5) * 4 + (m >> 4)) * 512 + (((((k >> 3) & 3) << 4) | (m & 15)) * 8) + (k & 7));
}

// ---------------------------------------------------------------------------
// Pack cat(W,U) [2048 x 4096] fp32 -> fp16 B-fragment-linear, z-cols reordered
// as col' = j*4 + g. Per (cg, kstep) a contiguous 1KB fragment tile.
// ---------------------------------------------------------------------------
__global__ __launch_bounds__(64) void k_pack(
    const float* __restrict__ W, const float* __restrict__ U, f16* __restrict__ out)
{
    const int kstep = blockIdx.x, cg = blockIdx.y, l = threadIdx.x;
    const int n = l & 15, q = l >> 4;
    const int stdcol = (n & 3) * HH + cg * 4 + (n >> 2);
    f16x8 v;
#pragma unroll
    for (int e = 0; e < 8; ++e) {
        int k = kstep * 32 + q * 8 + e;
        float s = (k < DIN) ? W[(size_t)k * G4 + stdcol] : U[(size_t)(k - DIN) * G4 + stdcol];
        v[e] = (f16)s;
    }
    *(f16x8*)(out + ((size_t)(cg * 64 + kstep) * 64 + l) * 8) = v;
}

// ---------------------------------------------------------------------------
// Kernel 1: XinF[t] = tanh(x[b][t][:] @ Wi + bi), written fp16 A-frag layout.
// ---------------------------------------------------------------------------
__global__ __launch_bounds__(256) void k_dense_in(
    const float* __restrict__ x, const float* __restrict__ Wi,
    const float* __restrict__ bi, f16* __restrict__ XinF)
{
    __shared__ float xs[16][FF];   // 32 KB
    const int jb  = blockIdx.x;
    const int rb  = blockIdx.y;
    const int tid = threadIdx.x;

    const float4* xsrc = (const float4*)(x + (size_t)rb * 16 * FF);
    float4* xdst = (float4*)(&xs[0][0]);
#pragma unroll
    for (int i = 0; i < 8; ++i) xdst[tid + i * 256] = xsrc[tid + i * 256];
    __syncthreads();

    const int j = jb * 256 + tid;
    float acc[16];
#pragma unroll
    for (int r = 0; r < 16; ++r) acc[r] = 0.f;

    for (int k = 0; k < FF; ++k) {
        float w = Wi[(size_t)k * DIN + j];
#pragma unroll
        for (int r = 0; r < 16; ++r) acc[r] += xs[r][k] * w;
    }
    const float bbv = bi[j];
#pragma unroll
    for (int r = 0; r < 16; ++r) {
        int g = rb * 16 + r;
        int b = g >> 9;
        int t = g & 511;
        XinF[(size_t)t * (BB * DIN) + afrag_off(b, j)] = (f16)tanhf(acc[r] + bbv);
    }
}

// ---------------------------------------------------------------------------
// Persistent cooperative kernel: all 513 pipeline phases in one launch.
// Grid 256 blocks x 512 threads (1 block/CU, 8 waves = 2/SIMD).
// Block role: lay = blockIdx&1, cgb = blockIdx>>1 (8 hidden units = 2 N-tiles).
// B-fragments for the block's columns are loaded ONCE into registers
// (8 ksteps x 2 N x 16B/lane = 64 VGPRs/lane), so per-phase weight traffic
// is zero. Phase p: L0 cell @ t=p (p<512), L1 cell @ t=p-1 (p>0);
// grid.sync() between phases orders h handoff device-wide.
// ---------------------------------------------------------------------------
__global__ __launch_bounds__(512, 2) void k_persist(
    const f16* __restrict__ XinF,
    f16* __restrict__ h0p0, f16* __restrict__ h0p1,
    f16* __restrict__ h1p0, f16* __restrict__ h1p1,
    const f16* __restrict__ pW0, const f16* __restrict__ pW1,
    const float* __restrict__ b0, const float* __restrict__ b1,
    float* __restrict__ c0, float* __restrict__ c1)
{
    cg::grid_group grid = cg::this_grid();

    const int lay = blockIdx.x & 1;
    const int cgb = blockIdx.x >> 1;
    const int tid  = threadIdx.x;
    const int ks   = tid >> 6;     // 0..7 wave = K-split slice
    const int lane = tid & 63;

    const f16* Bp     = lay ? pW1 : pW0;
    const float* bias = lay ? b1 : b0;
    float* c          = lay ? c1 : c0;

    // ---- load B fragments into registers (once) ----
    const f16* Bq0 = Bp + ((size_t)((cgb * 2 + 0) * 64 + ks * 8) * 64 + lane) * 8;
    const f16* Bq1 = Bp + ((size_t)((cgb * 2 + 1) * 64 + ks * 8) * 64 + lane) * 8;
    f16x8 breg0[8], breg1[8];
#pragma unroll
    for (int i = 0; i < 8; ++i) {
        breg0[i] = *(const f16x8*)(Bq0 + (size_t)i * 512);
        breg1[i] = *(const f16x8*)(Bq1 + (size_t)i * 512);
    }

    // ---- epilogue-role constants (thread -> (row, j)) ----
    const int row = tid & 63;
    const int jq  = tid >> 6;
    const int nn  = jq >> 2, jqi = jq & 3;
    const int jg  = (cgb * 2 + nn) * 4 + jqi;
    const int mt  = row >> 4, sub = row & 15;
    const int slq = (sub >> 2) << 4, reg = sub & 3;
    const int cidx = row * HH + jg;
    float bz[4];
#pragma unroll
    for (int g = 0; g < 4; ++g) bz[g] = bias[g * HH + jg];

    const size_t ABUF = (size_t)BB * DIN;
    const size_t kloc = (size_t)((ks & 3) * 8 * 4) * 512;   // A-half elem offset

    __shared__ float red[8][4][2][64][4];   // 64 KB

    for (int p = 0; p <= TT; ++p) {
        const bool active = lay ? (p > 0) : (p < TT);
        if (active) {
            const int wp = p & 1, rp = wp ^ 1;
            const f16* h0r = rp ? h0p1 : h0p0;
            const f16* A1 = lay ? h0r : (XinF + (size_t)p * ABUF);
            const f16* A2 = lay ? (rp ? h1p1 : h1p0) : h0r;
            f16* hw = lay ? (wp ? h1p1 : h1p0) : (wp ? h0p1 : h0p0);
            const f16* Ap = ((ks < 4) ? A1 : A2) + kloc + (size_t)lane * 8;

            f32x4 acc[4][2];
#pragma unroll
            for (int m = 0; m < 4; ++m)
#pragma unroll
                for (int n = 0; n < 2; ++n) acc[m][n] = (f32x4){0.f, 0.f, 0.f, 0.f};

#pragma unroll
            for (int i = 0; i < 8; ++i) {
#pragma unroll
                for (int m = 0; m < 4; ++m) {
                    f16x8 af = *(const f16x8*)(Ap + ((size_t)i * 4 + m) * 512);
                    acc[m][0] = __builtin_amdgcn_mfma_f32_16x16x32_f16(af, breg0[i], acc[m][0], 0, 0, 0);
                    acc[m][1] = __builtin_amdgcn_mfma_f32_16x16x32_f16(af, breg1[i], acc[m][1], 0, 0, 0);
                }
            }

#pragma unroll
            for (int m = 0; m < 4; ++m)
#pragma unroll
                for (int n = 0; n < 2; ++n)
                    *(f32x4*)&red[ks][m][n][lane][0] = acc[m][n];
            __syncthreads();

            // epilogue: C/D layout col=lane&15, row=(lane>>4)*4+reg
            float z[4];
#pragma unroll
            for (int g = 0; g < 4; ++g) {
                const int sl = slq | (jqi * 4 + g);
                float s = 0.f;
#pragma unroll
                for (int kk = 0; kk < 8; ++kk) s += red[kk][mt][nn][sl][reg];
                z[g] = s + bz[g];
            }
            const float ig = 1.f / (1.f + expf(-z[0]));
            const float fg = 1.f / (1.f + expf(-z[1]));
            const float cc = tanhf(z[2]);
            const float og = 1.f / (1.f + expf(-z[3]));
            const float cn = fg * c[cidx] + ig * cc;
            c[cidx] = cn;
            hw[afrag_off(row, jg)] = (f16)(og * tanhf(cn));
            __syncthreads();   // red reused next phase
        }
        grid.sync();
    }
}

// ---------------------------------------------------------------------------
// Kernel 3: out[b][o] = tanh(h1[b,:] @ Wo[:,o] + bo[o]); h1 in fp16 A-frag.
// ---------------------------------------------------------------------------
__global__ __launch_bounds__(128) void k_out(
    const f16* __restrict__ h1f, const float* __restrict__ Wo,
    const float* __restrict__ bo, float* __restrict__ out)
{
    __shared__ float hs[HH];
    const int b = blockIdx.x;
    for (int i = threadIdx.x; i < HH; i += 128) hs[i] = (float)h1f[afrag_off(b, i)];
    __syncthreads();
    const int o = threadIdx.x;
    float acc = 0.f;
    for (int k = 0; k < HH; ++k) acc += hs[k] * Wo[k * DOUT + o];
    out[b * DOUT + o] = tanhf(acc + bo[o]);
}

// ---------------------------------------------------------------------------
extern "C" void kernel_launch(void* const* d_in, const int* in_sizes, int n_in,
                              void* d_out, int out_size, void* d_ws, size_t ws_size,
                              hipStream_t stream)
{
    const float* x  = (const float*)d_in[0];
    const float* Wi = (const float*)d_in[1];
    const float* bi = (const float*)d_in[2];
    const float* W0 = (const float*)d_in[3];
    const float* U0 = (const float*)d_in[4];
    const float* b0 = (const float*)d_in[5];
    const float* W1 = (const float*)d_in[6];
    const float* U1 = (const float*)d_in[7];
    const float* b1 = (const float*)d_in[8];
    const float* Wo = (const float*)d_in[9];
    const float* bo = (const float*)d_in[10];
    float* out = (float*)d_out;

    f16* ws16 = (f16*)d_ws;
    const size_t ABUF = (size_t)BB * DIN;
    f16* XinF = ws16;
    f16* pW0  = XinF + (size_t)TT * ABUF;
    f16* pW1  = pW0 + (size_t)2048 * G4;
    f16* h0a  = pW1 + (size_t)2048 * G4;
    f16* h0b  = h0a + ABUF;
    f16* h1a  = h0b + ABUF;
    f16* h1b  = h1a + ABUF;
    float* c0 = (float*)(h1b + ABUF);
    float* c1 = c0 + ABUF;

    // zero h (both parities) and c — contiguous region
    hipMemsetAsync(h0a, 0, 4 * ABUF * sizeof(f16) + 2 * ABUF * sizeof(float), stream);

    k_pack<<<dim3(64, 256), 64, 0, stream>>>(W0, U0, pW0);
    k_pack<<<dim3(64, 256), 64, 0, stream>>>(W1, U1, pW1);
    k_dense_in<<<dim3(DIN / 256, (BB * TT) / 16), 256, 0, stream>>>(x, Wi, bi, XinF);

    {
        const f16* XinF_c = XinF;
        const f16* pW0_c = pW0;
        const f16* pW1_c = pW1;
        f16 *h0a_v = h0a, *h0b_v = h0b, *h1a_v = h1a, *h1b_v = h1b;
        float *c0_v = c0, *c1_v = c1;
        const float *b0_v = b0, *b1_v = b1;
        void* kargs[] = {
            (void*)&XinF_c,
            (void*)&h0a_v, (void*)&h0b_v, (void*)&h1a_v, (void*)&h1b_v,
            (void*)&pW0_c, (void*)&pW1_c,
            (void*)&b0_v, (void*)&b1_v,
            (void*)&c0_v, (void*)&c1_v
        };
        hipLaunchCooperativeKernel((void*)k_persist, dim3(256), dim3(512),
                                   kargs, 0, stream);
    }

    // phase TT writes parity 0 -> h1a holds h1[T-1]
    k_out<<<BB, 128, 0, stream>>>(h1a, Wo, bo, out);
}